// Round 1
// baseline (917.052 us; speedup 1.0000x reference)
//
#include <hip/hip_runtime.h>
#include <hip/hip_bf16.h>
#include <cstdint>

// Shapes: B=512, S=196, I=2048, Q=1024, H=512
// Key insight: _attn on (B,1,Q) input is identity (softmax over singleton axis),
// so ques_attn == ques_feat exactly. Only img_attn needs computing:
//   cc[b][h]  = sum_q qf[b][q]*w2g[q][h] + b2g[h] + b2x[h]
//   score[b][s] = sum_h tanh( sum_k X[b][s][k]*w2x[k][h] + cc[b][h] ) * w2h[h]   (b2h dropped: softmax shift-invariant)
//   a = softmax_s(score);  img_attn[b][f] = sum_s a[b][s] * X[b][s][f]

typedef __attribute__((ext_vector_type(8))) short bf16x8;
typedef __attribute__((ext_vector_type(4))) float f32x4;

__device__ inline unsigned short f2bf(float f) {
    union { float f; unsigned u; } v; v.f = f;
    unsigned u = v.u;
    u += 0x7FFFu + ((u >> 16) & 1u);   // round-to-nearest-even
    return (unsigned short)(u >> 16);
}

// ---------------- out0 = ques_feat (exact copy) ----------------
__global__ void k_copy(const float* __restrict__ src, float* __restrict__ dst) {
    int i = blockIdx.x * blockDim.x + threadIdx.x;
    reinterpret_cast<float4*>(dst)[i] = reinterpret_cast<const float4*>(src)[i];
}

// ---------------- WT[h][k] = bf16(w2x[k][h]) ----------------
__global__ void k_transpose_w(const float* __restrict__ w, unsigned short* __restrict__ wt) {
    __shared__ float tile[32][33];
    int k0 = (blockIdx.x & 63) * 32;   // 2048/32
    int h0 = (blockIdx.x >> 6) * 32;   // 512/32
    int tx = threadIdx.x & 31, ty = threadIdx.x >> 5;  // 256 threads
    #pragma unroll
    for (int j = 0; j < 4; ++j)
        tile[ty + j * 8][tx] = w[(size_t)(k0 + ty + j * 8) * 512 + h0 + tx];
    __syncthreads();
    #pragma unroll
    for (int j = 0; j < 4; ++j)
        wt[(size_t)(h0 + ty + j * 8) * 2048 + k0 + tx] = f2bf(tile[tx][ty + j * 8]);
}

// ---------------- cc[b][h] = qf[b]·w2g[:,h] + b2g[h] + b2x[h] ----------------
__global__ void k_cconst(const float* __restrict__ qf, const float* __restrict__ w2g,
                         const float* __restrict__ b2g, const float* __restrict__ b2x,
                         float* __restrict__ cc) {
    __shared__ float qls[8][1024];
    int b0 = blockIdx.x * 8;
    int t = threadIdx.x;  // 256
    #pragma unroll
    for (int j = 0; j < 8; ++j) {
        int idx = j * 256 + t;                   // 2048 float4 chunks
        int bb = idx >> 8, c4 = idx & 255;
        float4 v = reinterpret_cast<const float4*>(qf + (size_t)(b0 + bb) * 1024)[c4];
        qls[bb][c4 * 4 + 0] = v.x; qls[bb][c4 * 4 + 1] = v.y;
        qls[bb][c4 * 4 + 2] = v.z; qls[bb][c4 * 4 + 3] = v.w;
    }
    __syncthreads();
    float acc0[8], acc1[8];
    #pragma unroll
    for (int bb = 0; bb < 8; ++bb) { acc0[bb] = 0.f; acc1[bb] = 0.f; }
    #pragma unroll 4
    for (int q = 0; q < 1024; ++q) {
        float w0 = w2g[q * 512 + t];
        float w1 = w2g[q * 512 + 256 + t];
        #pragma unroll
        for (int bb = 0; bb < 8; ++bb) {
            float qv = qls[bb][q];
            acc0[bb] += qv * w0;
            acc1[bb] += qv * w1;
        }
    }
    float c0 = b2g[t] + b2x[t];
    float c1 = b2g[t + 256] + b2x[t + 256];
    #pragma unroll
    for (int bb = 0; bb < 8; ++bb) {
        cc[(size_t)(b0 + bb) * 512 + t] = acc0[bb] + c0;
        cc[(size_t)(b0 + bb) * 512 + t + 256] = acc1[bb] + c1;
    }
}

// ---------------- scores: fused GEMM + tanh + dot(w2h) ----------------
// grid 1024 = (b, s-half); block 512 = 8 waves. Block tile: M=98(pad 112) x N=512, K=2048 step 32.
// Wave w owns N-slice [w*64, w*64+64): acc[7][4] f32x4 = 112 VGPRs.
#define LSTR 40   // LDS row stride (bf16): 80B = 20 banks -> only 2-way (free) conflicts; 16B-aligned
__global__ __launch_bounds__(512) void k_scores(
    const float* __restrict__ X, const unsigned short* __restrict__ WT,
    const float* __restrict__ cc, const float* __restrict__ w2h,
    float* __restrict__ scores)
{
    __shared__ __align__(16) unsigned short Alds[112 * LSTR];
    __shared__ __align__(16) unsigned short Blds[512 * LSTR];
    __shared__ float slds[112];

    int bx = blockIdx.x;
    int b = bx >> 1;
    int s0 = (bx & 1) * 98;
    int tid = threadIdx.x;
    int wave = tid >> 6, lane = tid & 63;
    int l15 = lane & 15, l4 = lane >> 4;

    // zero pad rows (98..111) once; zero score accumulator
    for (int i = tid; i < 14 * LSTR; i += 512) Alds[98 * LSTR + i] = 0;
    if (tid < 112) slds[tid] = 0.0f;

    f32x4 acc[7][4];
    #pragma unroll
    for (int m = 0; m < 7; ++m)
        #pragma unroll
        for (int n = 0; n < 4; ++n) acc[m][n] = (f32x4){0.f, 0.f, 0.f, 0.f};

    const float* Xb = X + (size_t)(b * 196 + s0) * 2048;

    for (int k0 = 0; k0 < 2048; k0 += 32) {
        __syncthreads();
        // stage A: 98 rows x 32 fp32 -> bf16 (784 float4 chunks)
        #pragma unroll
        for (int r = 0; r < 2; ++r) {
            int id = r * 512 + tid;
            if (id < 784) {
                int row = id >> 3, c4 = id & 7;
                float4 v = *reinterpret_cast<const float4*>(Xb + (size_t)row * 2048 + k0 + c4 * 4);
                ushort4 o;
                o.x = f2bf(v.x); o.y = f2bf(v.y); o.z = f2bf(v.z); o.w = f2bf(v.w);
                *reinterpret_cast<ushort4*>(&Alds[row * LSTR + c4 * 4]) = o;
            }
        }
        // stage B: WT rows 0..511, 32 bf16 each (2048 16B chunks)
        #pragma unroll
        for (int r = 0; r < 4; ++r) {
            int id = r * 512 + tid;
            int row = id >> 2, c = id & 3;
            uint4 v = *reinterpret_cast<const uint4*>(WT + (size_t)row * 2048 + k0 + c * 8);
            *reinterpret_cast<uint4*>(&Blds[row * LSTR + c * 8]) = v;
        }
        __syncthreads();
        // MFMA phase
        int koff = l4 * 8;
        bf16x8 bf[4];
        #pragma unroll
        for (int n = 0; n < 4; ++n) {
            int col = wave * 64 + n * 16 + l15;
            bf[n] = *reinterpret_cast<const bf16x8*>(&Blds[col * LSTR + koff]);
        }
        #pragma unroll
        for (int m = 0; m < 7; ++m) {
            bf16x8 af = *reinterpret_cast<const bf16x8*>(&Alds[(m * 16 + l15) * LSTR + koff]);
            #pragma unroll
            for (int n = 0; n < 4; ++n)
                acc[m][n] = __builtin_amdgcn_mfma_f32_16x16x32_bf16(af, bf[n], acc[m][n], 0, 0, 0);
        }
    }

    // epilogue: score[s] = sum_h tanh(feat + cc[h]) * w2h[h]
    float cch[4], whv[4];
    #pragma unroll
    for (int n = 0; n < 4; ++n) {
        int h = wave * 64 + n * 16 + l15;
        cch[n] = cc[(size_t)b * 512 + h];
        whv[n] = w2h[h];
    }
    #pragma unroll
    for (int m = 0; m < 7; ++m) {
        #pragma unroll
        for (int i = 0; i < 4; ++i) {
            float p = 0.0f;
            #pragma unroll
            for (int n = 0; n < 4; ++n) {
                float x = acc[m][n][i] + cch[n];
                float th = 1.0f - 2.0f / (__expf(2.0f * x) + 1.0f);
                p += th * whv[n];
            }
            // D layout: col = lane&15 (=h), row = (lane>>4)*4 + i (=s). Reduce over the 16 h-lanes.
            p += __shfl_xor(p, 1);
            p += __shfl_xor(p, 2);
            p += __shfl_xor(p, 4);
            p += __shfl_xor(p, 8);
            if (l15 == 0) atomicAdd(&slds[m * 16 + l4 * 4 + i], p);
        }
    }
    __syncthreads();
    if (tid < 98) scores[(size_t)b * 208 + s0 + tid] = slds[tid];
}

// ---------------- softmax over s (196) per b ----------------
__global__ void k_softmax(float* sc) {
    int b = blockIdx.x, t = threadIdx.x;  // 256 threads = 4 waves
    __shared__ float red[8];
    float v = (t < 196) ? sc[(size_t)b * 208 + t] : -3.0e38f;
    float m = v;
    for (int o = 32; o > 0; o >>= 1) m = fmaxf(m, __shfl_xor(m, o));
    if ((t & 63) == 0) red[t >> 6] = m;
    __syncthreads();
    m = fmaxf(fmaxf(red[0], red[1]), fmaxf(red[2], red[3]));
    float e = (t < 196) ? __expf(v - m) : 0.0f;
    float s = e;
    for (int o = 32; o > 0; o >>= 1) s += __shfl_xor(s, o);
    if ((t & 63) == 0) red[4 + (t >> 6)] = s;
    __syncthreads();
    float tot = red[4] + red[5] + red[6] + red[7];
    if (t < 196) sc[(size_t)b * 208 + t] = e / tot;
}

// ---------------- img_attn[b][f] = sum_s a[b][s] * X[b][s][f] ----------------
__global__ void k_wsum(const float* __restrict__ X, const float* __restrict__ a,
                       float* __restrict__ out1) {
    __shared__ float als[196];
    int b = blockIdx.x >> 1;
    int fh = (blockIdx.x & 1) * 1024;
    int t = threadIdx.x;  // 256
    if (t < 196) als[t] = a[(size_t)b * 208 + t];
    __syncthreads();
    int f = fh + t * 4;
    const float* Xb = X + (size_t)b * 196 * 2048 + f;
    float4 acc = {0.f, 0.f, 0.f, 0.f};
    #pragma unroll 4
    for (int s = 0; s < 196; ++s) {
        float4 x = *reinterpret_cast<const float4*>(Xb + (size_t)s * 2048);
        float w = als[s];
        acc.x += w * x.x; acc.y += w * x.y; acc.z += w * x.z; acc.w += w * x.w;
    }
    *reinterpret_cast<float4*>(out1 + (size_t)b * 2048 + f) = acc;
}

extern "C" void kernel_launch(void* const* d_in, const int* in_sizes, int n_in,
                              void* d_out, int out_size, void* d_ws, size_t ws_size,
                              hipStream_t stream) {
    const float* qf  = (const float*)d_in[0];
    const float* X   = (const float*)d_in[1];
    const float* w2x = (const float*)d_in[6];
    const float* b2x = (const float*)d_in[7];
    const float* w2g = (const float*)d_in[8];
    const float* b2g = (const float*)d_in[9];
    const float* w2h = (const float*)d_in[10];

    float* out0 = (float*)d_out;                 // ques_attn = ques_feat (512x1024)
    float* out1 = out0 + 512 * 1024;             // img_attn (512x2048)

    // ws layout: [0,2MB) WT bf16 (512x2048); [2MB,3MB) cc f32 (512x512); [3MB,..) scores f32 (512x208)
    unsigned short* WT = (unsigned short*)d_ws;
    float* cc = (float*)((char*)d_ws + (size_t)(2u << 20));
    float* sc = (float*)((char*)d_ws + (size_t)(3u << 20));

    k_copy<<<512, 256, 0, stream>>>(qf, out0);
    k_transpose_w<<<1024, 256, 0, stream>>>(w2x, WT);
    k_cconst<<<64, 256, 0, stream>>>(qf, w2g, b2g, b2x, cc);
    k_scores<<<1024, 512, 0, stream>>>(X, WT, cc, w2h, sc);
    k_softmax<<<512, 256, 0, stream>>>(sc);
    k_wsum<<<1024, 256, 0, stream>>>(X, sc, out1);
}

// Round 2
// 664.165 us; speedup vs baseline: 1.3808x; 1.3808x over previous
//
#include <hip/hip_runtime.h>
#include <hip/hip_bf16.h>
#include <cstdint>

// Shapes: B=512, S=196, I=2048, Q=1024, H=512
// ques_attn == ques_feat exactly (softmax over singleton axis). Only img_attn computed:
//   cc[b][h]  = sum_q qf[b][q]*w2g[q][h] + b2g[h] + b2x[h]
//   score[b][s] = sum_h tanh( sum_k X[b][s][k]*w2x[k][h] + cc[b][h] ) * w2h[h]  (b2h dropped)
//   a = softmax_s(score);  img_attn[b][f] = sum_s a[b][s] * X[b][s][f]

typedef __attribute__((ext_vector_type(8))) short bf16x8;
typedef __attribute__((ext_vector_type(4))) float f32x4;

__device__ inline unsigned short f2bf(float f) {
    union { float f; unsigned u; } v; v.f = f;
    unsigned u = v.u;
    u += 0x7FFFu + ((u >> 16) & 1u);
    return (unsigned short)(u >> 16);
}

__device__ inline unsigned pk2(float lo, float hi) {
    __hip_bfloat162 h = __float22bfloat162_rn(make_float2(lo, hi));
    return *reinterpret_cast<unsigned*>(&h);
}

// ---------------- out0 = ques_feat (exact copy) ----------------
__global__ void k_copy(const float* __restrict__ src, float* __restrict__ dst) {
    int i = blockIdx.x * blockDim.x + threadIdx.x;
    reinterpret_cast<float4*>(dst)[i] = reinterpret_cast<const float4*>(src)[i];
}

// ---------------- WT[h][k] = bf16(w2x[k][h]) ----------------
__global__ void k_transpose_w(const float* __restrict__ w, unsigned short* __restrict__ wt) {
    __shared__ float tile[32][33];
    int k0 = (blockIdx.x & 63) * 32;
    int h0 = (blockIdx.x >> 6) * 32;
    int tx = threadIdx.x & 31, ty = threadIdx.x >> 5;
    #pragma unroll
    for (int j = 0; j < 4; ++j)
        tile[ty + j * 8][tx] = w[(size_t)(k0 + ty + j * 8) * 512 + h0 + tx];
    __syncthreads();
    #pragma unroll
    for (int j = 0; j < 4; ++j)
        wt[(size_t)(h0 + ty + j * 8) * 2048 + k0 + tx] = f2bf(tile[tx][ty + j * 8]);
}

// ---------------- cc[b][h] = qf[b]·w2g[:,h] + b2g[h] + b2x[h] ----------------
// 256 blocks x 256 threads; 2 b-rows per block, 2 h-cols per thread.
__global__ void k_cconst(const float* __restrict__ qf, const float* __restrict__ w2g,
                         const float* __restrict__ b2g, const float* __restrict__ b2x,
                         float* __restrict__ cc) {
    __shared__ float qls[2][1024];
    int b0 = blockIdx.x * 2;
    int t = threadIdx.x;
    #pragma unroll
    for (int j = 0; j < 2; ++j) {
        int idx = j * 256 + t;                    // 512 float4 chunks
        int bb = idx >> 8, c4 = idx & 255;
        float4 v = reinterpret_cast<const float4*>(qf + (size_t)(b0 + bb) * 1024)[c4];
        qls[bb][c4 * 4 + 0] = v.x; qls[bb][c4 * 4 + 1] = v.y;
        qls[bb][c4 * 4 + 2] = v.z; qls[bb][c4 * 4 + 3] = v.w;
    }
    __syncthreads();
    float a00 = 0.f, a01 = 0.f, a10 = 0.f, a11 = 0.f;
    #pragma unroll 8
    for (int q = 0; q < 1024; ++q) {
        float w0 = w2g[q * 512 + t];
        float w1 = w2g[q * 512 + 256 + t];
        float q0 = qls[0][q], q1 = qls[1][q];
        a00 += q0 * w0; a01 += q0 * w1;
        a10 += q1 * w0; a11 += q1 * w1;
    }
    float c0 = b2g[t] + b2x[t];
    float c1 = b2g[t + 256] + b2x[t + 256];
    cc[(size_t)b0 * 512 + t] = a00 + c0;
    cc[(size_t)b0 * 512 + t + 256] = a01 + c1;
    cc[(size_t)(b0 + 1) * 512 + t] = a10 + c0;
    cc[(size_t)(b0 + 1) * 512 + t + 256] = a11 + c1;
}

// ---------------- scores: fused GEMM + tanh + dot(w2h) ----------------
// grid 1024 = (b, s-half); block 512 = 8 waves, each wave owns a 64-col N slice.
// Tile M=98(pad112) x N=512, K-step 64, A-only LDS double-buffered (XOR-16B swizzle),
// B fragments straight from L2 (WT, 2MB, hot), register ping-pong across K-steps.
#define NSTEP 32   // 2048/64
struct ScoresCtx {
    const float* Xb; const unsigned short* WT; unsigned short* xbf;
    unsigned short (*A)[112 * 64];
    int tid, wave, l15, l4, do_xbf; size_t xbase;
};

__device__ __forceinline__ void sc_xload(const ScoresCtx& c, int t, float4 xv[2][2]) {
    int k0 = t * 64;
    #pragma unroll
    for (int u = 0; u < 2; ++u) {
        int id = c.tid + u * 512;
        if (id < 784) {
            int row = id >> 3, cc8 = id & 7;
            const float* p = c.Xb + (size_t)row * 2048 + k0 + cc8 * 8;
            xv[u][0] = *reinterpret_cast<const float4*>(p);
            xv[u][1] = *reinterpret_cast<const float4*>(p + 4);
        }
    }
}

__device__ __forceinline__ void sc_bload(const ScoresCtx& c, int t, bf16x8 br[8]) {
    int k0 = t * 64;
    #pragma unroll
    for (int kh = 0; kh < 2; ++kh)
        #pragma unroll
        for (int n = 0; n < 4; ++n) {
            int col = c.wave * 64 + n * 16 + c.l15;
            br[kh * 4 + n] = *reinterpret_cast<const bf16x8*>(
                c.WT + (size_t)col * 2048 + k0 + kh * 32 + c.l4 * 8);
        }
}

__device__ __forceinline__ void sc_stagewrite(const ScoresCtx& c, int t, float4 xv[2][2]) {
    int buf = t & 1, k0 = t * 64;
    #pragma unroll
    for (int u = 0; u < 2; ++u) {
        int id = c.tid + u * 512;
        if (id < 784) {
            int row = id >> 3, cc8 = id & 7;
            uint4 o;
            o.x = pk2(xv[u][0].x, xv[u][0].y);
            o.y = pk2(xv[u][0].z, xv[u][0].w);
            o.z = pk2(xv[u][1].x, xv[u][1].y);
            o.w = pk2(xv[u][1].z, xv[u][1].w);
            int idx = row * 64 + ((((cc8 * 16) ^ ((row & 7) << 4))) >> 1);
            *reinterpret_cast<uint4*>(&c.A[buf][idx]) = o;
            if (c.do_xbf)
                *reinterpret_cast<uint4*>(c.xbf + c.xbase + (size_t)row * 2048 + k0 + cc8 * 8) = o;
        }
    }
}

__device__ __forceinline__ void sc_compute(const ScoresCtx& c, int t, bf16x8 br[8],
                                           f32x4 acc[7][4]) {
    int buf = t & 1;
    #pragma unroll
    for (int kh = 0; kh < 2; ++kh) {
        #pragma unroll
        for (int m = 0; m < 7; ++m) {
            int row = m * 16 + c.l15;
            int bofs = (kh * 64 + c.l4 * 16) ^ ((c.l15 & 7) << 4);
            bf16x8 af = *reinterpret_cast<const bf16x8*>(&c.A[buf][row * 64 + (bofs >> 1)]);
            #pragma unroll
            for (int n = 0; n < 4; ++n)
                acc[m][n] = __builtin_amdgcn_mfma_f32_16x16x32_bf16(af, br[kh * 4 + n],
                                                                    acc[m][n], 0, 0, 0);
        }
    }
}

__global__ __launch_bounds__(512, 2) void k_scores(
    const float* __restrict__ X, const unsigned short* __restrict__ WT,
    const float* __restrict__ cc, const float* __restrict__ w2h,
    float* __restrict__ scores, unsigned short* __restrict__ xbf, int do_xbf)
{
    __shared__ __align__(16) unsigned short A[2][112 * 64];
    __shared__ float slds[112];

    int bx = blockIdx.x;
    int b = bx >> 1;
    int s0 = (bx & 1) * 98;
    int tid = threadIdx.x;
    int wave = tid >> 6, lane = tid & 63;
    int l15 = lane & 15, l4 = lane >> 4;

    ScoresCtx c;
    c.Xb = X + (size_t)(b * 196 + s0) * 2048;
    c.WT = WT; c.xbf = xbf; c.A = A;
    c.tid = tid; c.wave = wave; c.l15 = l15; c.l4 = l4; c.do_xbf = do_xbf;
    c.xbase = (size_t)(b * 196 + s0) * 2048;

    // zero LDS pad rows (98..111) in both buffers; zero score accumulator
    for (int i = tid; i < 14 * 64; i += 512) { A[0][98 * 64 + i] = 0; A[1][98 * 64 + i] = 0; }
    if (tid < 112) slds[tid] = 0.0f;

    f32x4 acc[7][4];
    #pragma unroll
    for (int m = 0; m < 7; ++m)
        #pragma unroll
        for (int n = 0; n < 4; ++n) acc[m][n] = (f32x4){0.f, 0.f, 0.f, 0.f};

    bf16x8 bregA[8], bregB[8];
    float4 xv[2][2];

    // prologue: stage tile 0, load B(0)
    sc_xload(c, 0, xv);
    sc_bload(c, 0, bregA);
    sc_stagewrite(c, 0, xv);
    __syncthreads();

    for (int t2 = 0; t2 < NSTEP; t2 += 2) {
        // even step: uses bregA, prefetches bregB
        {
            int t = t2;
            if (t + 1 < NSTEP) { sc_xload(c, t + 1, xv); sc_bload(c, t + 1, bregB); }
            sc_compute(c, t, bregA, acc);
            if (t + 1 < NSTEP) sc_stagewrite(c, t + 1, xv);
            __syncthreads();
        }
        // odd step: uses bregB, prefetches bregA
        {
            int t = t2 + 1;
            if (t + 1 < NSTEP) { sc_xload(c, t + 1, xv); sc_bload(c, t + 1, bregA); }
            sc_compute(c, t, bregB, acc);
            if (t + 1 < NSTEP) sc_stagewrite(c, t + 1, xv);
            __syncthreads();
        }
    }

    // epilogue: score[s] = sum_h tanh(feat + cc[h]) * w2h[h]
    float cch[4], whv[4];
    #pragma unroll
    for (int n = 0; n < 4; ++n) {
        int h = wave * 64 + n * 16 + l15;
        cch[n] = cc[(size_t)b * 512 + h];
        whv[n] = w2h[h];
    }
    #pragma unroll
    for (int m = 0; m < 7; ++m) {
        #pragma unroll
        for (int i = 0; i < 4; ++i) {
            float p = 0.0f;
            #pragma unroll
            for (int n = 0; n < 4; ++n) {
                float x = acc[m][n][i] + cch[n];
                float th = 1.0f - 2.0f / (__expf(2.0f * x) + 1.0f);
                p += th * whv[n];
            }
            p += __shfl_xor(p, 1);
            p += __shfl_xor(p, 2);
            p += __shfl_xor(p, 4);
            p += __shfl_xor(p, 8);
            if (l15 == 0) atomicAdd(&slds[m * 16 + l4 * 4 + i], p);
        }
    }
    __syncthreads();
    if (tid < 98) scores[(size_t)b * 208 + s0 + tid] = slds[tid];
}

// ---------------- softmax over s (196) per b ----------------
__global__ void k_softmax(float* sc) {
    int b = blockIdx.x, t = threadIdx.x;
    __shared__ float red[8];
    float v = (t < 196) ? sc[(size_t)b * 208 + t] : -3.0e38f;
    float m = v;
    for (int o = 32; o > 0; o >>= 1) m = fmaxf(m, __shfl_xor(m, o));
    if ((t & 63) == 0) red[t >> 6] = m;
    __syncthreads();
    m = fmaxf(fmaxf(red[0], red[1]), fmaxf(red[2], red[3]));
    float e = (t < 196) ? __expf(v - m) : 0.0f;
    float s = e;
    for (int o = 32; o > 0; o >>= 1) s += __shfl_xor(s, o);
    if ((t & 63) == 0) red[4 + (t >> 6)] = s;
    __syncthreads();
    float tot = red[4] + red[5] + red[6] + red[7];
    if (t < 196) sc[(size_t)b * 208 + t] = e / tot;
}

// ---------------- wsum, f32 path: img_attn[b][f] = sum_s a[b][s]*X[b][s][f] ----------------
__global__ void k_wsum(const float* __restrict__ X, const float* __restrict__ a,
                       float* __restrict__ out1) {
    __shared__ float als[196];
    int b = blockIdx.x >> 1;
    int fh = (blockIdx.x & 1) * 1024;
    int t = threadIdx.x;
    if (t < 196) als[t] = a[(size_t)b * 208 + t];
    __syncthreads();
    int f = fh + t * 4;
    const float* Xb = X + (size_t)b * 196 * 2048 + f;
    float4 acc = {0.f, 0.f, 0.f, 0.f};
    #pragma unroll 4
    for (int s = 0; s < 196; ++s) {
        float4 x = *reinterpret_cast<const float4*>(Xb + (size_t)s * 2048);
        float w = als[s];
        acc.x += w * x.x; acc.y += w * x.y; acc.z += w * x.z; acc.w += w * x.w;
    }
    *reinterpret_cast<float4*>(out1 + (size_t)b * 2048 + f) = acc;
}

// ---------------- wsum, bf16 path (reads Xbf written by k_scores) ----------------
__global__ void k_wsum_bf(const unsigned short* __restrict__ Xbf, const float* __restrict__ a,
                          float* __restrict__ out1) {
    __shared__ float als[196];
    int b = blockIdx.x >> 1;
    int fh = (blockIdx.x & 1) * 1024;
    int t = threadIdx.x;
    if (t < 196) als[t] = a[(size_t)b * 208 + t];
    __syncthreads();
    int f = fh + t * 4;   // 4 bf16 per thread
    const unsigned short* Xb = Xbf + (size_t)b * 196 * 2048 + f;
    float a0 = 0.f, a1 = 0.f, a2 = 0.f, a3 = 0.f;
    #pragma unroll 4
    for (int s = 0; s < 196; ++s) {
        ushort4 x = *reinterpret_cast<const ushort4*>(Xb + (size_t)s * 2048);
        float w = als[s];
        union { unsigned u; float f; } u0, u1, u2, u3;
        u0.u = (unsigned)x.x << 16; u1.u = (unsigned)x.y << 16;
        u2.u = (unsigned)x.z << 16; u3.u = (unsigned)x.w << 16;
        a0 += w * u0.f; a1 += w * u1.f; a2 += w * u2.f; a3 += w * u3.f;
    }
    float4 o = {a0, a1, a2, a3};
    *reinterpret_cast<float4*>(out1 + (size_t)b * 2048 + f) = o;
}

extern "C" void kernel_launch(void* const* d_in, const int* in_sizes, int n_in,
                              void* d_out, int out_size, void* d_ws, size_t ws_size,
                              hipStream_t stream) {
    const float* qf  = (const float*)d_in[0];
    const float* X   = (const float*)d_in[1];
    const float* w2x = (const float*)d_in[6];
    const float* b2x = (const float*)d_in[7];
    const float* w2g = (const float*)d_in[8];
    const float* b2g = (const float*)d_in[9];
    const float* w2h = (const float*)d_in[10];

    float* out0 = (float*)d_out;                 // ques_attn = ques_feat (512x1024)
    float* out1 = out0 + 512 * 1024;             // img_attn (512x2048)

    // ws layout: [0,2MB) WT bf16; [2MB,3MB) cc f32; [3MB,3.5MB) scores f32; [4MB,..) Xbf bf16
    unsigned short* WT = (unsigned short*)d_ws;
    float* cc = (float*)((char*)d_ws + (size_t)(2u << 20));
    float* sc = (float*)((char*)d_ws + (size_t)(3u << 20));
    const size_t XBF_BYTES = (size_t)512 * 196 * 2048 * 2;
    unsigned short* xbf = (unsigned short*)((char*)d_ws + (size_t)(4u << 20));
    int big = (ws_size >= (size_t)(4u << 20) + XBF_BYTES) ? 1 : 0;

    k_copy<<<512, 256, 0, stream>>>(qf, out0);
    k_transpose_w<<<1024, 256, 0, stream>>>(w2x, WT);
    k_cconst<<<256, 256, 0, stream>>>(qf, w2g, b2g, b2x, cc);
    k_scores<<<1024, 512, 0, stream>>>(X, WT, cc, w2h, sc, xbf, big);
    k_softmax<<<512, 256, 0, stream>>>(sc);
    if (big)
        k_wsum_bf<<<1024, 256, 0, stream>>>(xbf, sc, out1);
    else
        k_wsum<<<1024, 256, 0, stream>>>(X, sc, out1);
}

// Round 3
// 586.863 us; speedup vs baseline: 1.5626x; 1.1317x over previous
//
#include <hip/hip_runtime.h>
#include <hip/hip_bf16.h>
#include <cstdint>

// Shapes: B=512, S=196, I=2048, Q=1024, H=512
// ques_attn == ques_feat exactly (softmax over singleton axis). Only img_attn computed:
//   cc[b][h]  = sum_q qf[b][q]*w2g[q][h] + b2g[h] + b2x[h]
//   score[b][s] = sum_h tanh( sum_k X[b][s][k]*w2x[k][h] + cc[b][h] ) * w2h[h]  (b2h dropped)
//   a = softmax_s(score);  img_attn[b][f] = sum_s a[b][s] * X[b][s][f]

typedef __attribute__((ext_vector_type(8))) short bf16x8;
typedef __attribute__((ext_vector_type(4))) float f32x4;

__device__ inline unsigned short f2bf(float f) {
    union { float f; unsigned u; } v; v.f = f;
    unsigned u = v.u;
    u += 0x7FFFu + ((u >> 16) & 1u);
    return (unsigned short)(u >> 16);
}

__device__ inline unsigned pk2(float lo, float hi) {
    __hip_bfloat162 h = __float22bfloat162_rn(make_float2(lo, hi));
    return *reinterpret_cast<unsigned*>(&h);
}

// ---------------- out0 = ques_feat (exact copy) ----------------
__global__ void k_copy(const float* __restrict__ src, float* __restrict__ dst) {
    int i = blockIdx.x * blockDim.x + threadIdx.x;
    reinterpret_cast<float4*>(dst)[i] = reinterpret_cast<const float4*>(src)[i];
}

// ---------------- WTf: fragment-major packed bf16 of w2x^T ----------------
// Tile (kblk, nblk) = 64 k x 16 cols, laid out [kc8 0..7][col 0..15][j 0..7]:
// a wave's MFMA B-fragment load (16 cols x 32 k) is ONE contiguous 1 KB access.
// WTf[(kblk*32 + nblk)*1024 + kc8*128 + col*8 + j] = bf16(w2x[kblk*64 + kc8*8 + j][nblk*16 + col])
__global__ void k_pack_w(const float* __restrict__ w, unsigned short* __restrict__ wtf) {
    int kblk = blockIdx.x >> 5;   // 0..31
    int nblk = blockIdx.x & 31;   // 0..31
    int t = threadIdx.x;          // 128 threads: (kc8, col)
    int kc8 = t >> 4, col = t & 15;
    const float* src = w + (size_t)(kblk * 64 + kc8 * 8) * 512 + nblk * 16 + col;
    unsigned short* dst = wtf + (size_t)(kblk * 32 + nblk) * 1024 + kc8 * 128 + col * 8;
    unsigned short tmp[8];
    #pragma unroll
    for (int j = 0; j < 8; ++j) tmp[j] = f2bf(src[(size_t)j * 512]);
    *reinterpret_cast<uint4*>(dst) = *reinterpret_cast<const uint4*>(tmp);
}

// ---------------- cc[b][h] = qf[b]·w2g[:,h] + b2g[h] + b2x[h] ----------------
__global__ void k_cconst(const float* __restrict__ qf, const float* __restrict__ w2g,
                         const float* __restrict__ b2g, const float* __restrict__ b2x,
                         float* __restrict__ cc) {
    __shared__ float qls[2][1024];
    int b0 = blockIdx.x * 2;
    int t = threadIdx.x;
    #pragma unroll
    for (int j = 0; j < 2; ++j) {
        int idx = j * 256 + t;
        int bb = idx >> 8, c4 = idx & 255;
        float4 v = reinterpret_cast<const float4*>(qf + (size_t)(b0 + bb) * 1024)[c4];
        qls[bb][c4 * 4 + 0] = v.x; qls[bb][c4 * 4 + 1] = v.y;
        qls[bb][c4 * 4 + 2] = v.z; qls[bb][c4 * 4 + 3] = v.w;
    }
    __syncthreads();
    float a00 = 0.f, a01 = 0.f, a10 = 0.f, a11 = 0.f;
    #pragma unroll 8
    for (int q = 0; q < 1024; ++q) {
        float w0 = w2g[q * 512 + t];
        float w1 = w2g[q * 512 + 256 + t];
        float q0 = qls[0][q], q1 = qls[1][q];
        a00 += q0 * w0; a01 += q0 * w1;
        a10 += q1 * w0; a11 += q1 * w1;
    }
    float c0 = b2g[t] + b2x[t];
    float c1 = b2g[t + 256] + b2x[t + 256];
    cc[(size_t)b0 * 512 + t] = a00 + c0;
    cc[(size_t)b0 * 512 + t + 256] = a01 + c1;
    cc[(size_t)(b0 + 1) * 512 + t] = a10 + c0;
    cc[(size_t)(b0 + 1) * 512 + t + 256] = a11 + c1;
}

// ---------------- scores: fused GEMM + tanh + dot(w2h) ----------------
// grid 1024 = (b, s-half); block 512 = 8 waves, wave owns a 64-col N slice.
// Tile M=98(pad112) x N=512, K-step 64. A in LDS (double-buffered, XOR swizzle),
// 2-step-deep X register prefetch; B fragments contiguous from packed WTf (L2-hot).
#define NSTEP 32
struct ScoresCtx {
    const float* Xb; const unsigned short* WTf;
    unsigned short (*A)[112 * 64];
    int tid, wave, l15, l4;
};

__device__ __forceinline__ void sc_xload(const ScoresCtx& c, int t, float4 xv[2][2]) {
    int k0 = t * 64;
    #pragma unroll
    for (int u = 0; u < 2; ++u) {
        int id = c.tid + u * 512;
        if (id < 784) {
            int row = id >> 3, cc8 = id & 7;
            const float* p = c.Xb + (size_t)row * 2048 + k0 + cc8 * 8;
            xv[u][0] = *reinterpret_cast<const float4*>(p);
            xv[u][1] = *reinterpret_cast<const float4*>(p + 4);
        }
    }
}

__device__ __forceinline__ void sc_stagewrite(const ScoresCtx& c, int t, float4 xv[2][2]) {
    int buf = t & 1;
    #pragma unroll
    for (int u = 0; u < 2; ++u) {
        int id = c.tid + u * 512;
        if (id < 784) {
            int row = id >> 3, cc8 = id & 7;
            uint4 o;
            o.x = pk2(xv[u][0].x, xv[u][0].y);
            o.y = pk2(xv[u][0].z, xv[u][0].w);
            o.z = pk2(xv[u][1].x, xv[u][1].y);
            o.w = pk2(xv[u][1].z, xv[u][1].w);
            int idx = row * 64 + ((((cc8 * 16) ^ ((row & 7) << 4))) >> 1);
            *reinterpret_cast<uint4*>(&c.A[buf][idx]) = o;
        }
    }
}

__device__ __forceinline__ void sc_bload(const ScoresCtx& c, int t, bf16x8 br[8]) {
    // tile base for (kblk=t, nblk=wave*4): each (kh,n) read = contiguous 1 KB/wave
    const unsigned short* base = c.WTf + (size_t)t * 32768 + (size_t)c.wave * 4096;
    #pragma unroll
    for (int kh = 0; kh < 2; ++kh)
        #pragma unroll
        for (int n = 0; n < 4; ++n)
            br[kh * 4 + n] = *reinterpret_cast<const bf16x8*>(
                base + n * 1024 + (kh * 4 + c.l4) * 128 + c.l15 * 8);
}

__device__ __forceinline__ void sc_compute(const ScoresCtx& c, int t, bf16x8 br[8],
                                           f32x4 acc[7][4]) {
    int buf = t & 1;
    #pragma unroll
    for (int kh = 0; kh < 2; ++kh) {
        #pragma unroll
        for (int m = 0; m < 7; ++m) {
            int row = m * 16 + c.l15;
            int bofs = (kh * 64 + c.l4 * 16) ^ ((c.l15 & 7) << 4);
            bf16x8 af = *reinterpret_cast<const bf16x8*>(&c.A[buf][row * 64 + (bofs >> 1)]);
            #pragma unroll
            for (int n = 0; n < 4; ++n)
                acc[m][n] = __builtin_amdgcn_mfma_f32_16x16x32_bf16(af, br[kh * 4 + n],
                                                                    acc[m][n], 0, 0, 0);
        }
    }
}

__global__ __launch_bounds__(512, 2) void k_scores(
    const float* __restrict__ X, const unsigned short* __restrict__ WTf,
    const float* __restrict__ cc, const float* __restrict__ w2h,
    float* __restrict__ scores)
{
    __shared__ __align__(16) unsigned short A[2][112 * 64];
    __shared__ float slds[112];

    int bx = blockIdx.x;
    int b = bx >> 1;
    int s0 = (bx & 1) * 98;
    int tid = threadIdx.x;
    int wave = tid >> 6, lane = tid & 63;
    int l15 = lane & 15, l4 = lane >> 4;

    ScoresCtx c;
    c.Xb = X + (size_t)(b * 196 + s0) * 2048;
    c.WTf = WTf; c.A = A;
    c.tid = tid; c.wave = wave; c.l15 = l15; c.l4 = l4;

    // prefetch epilogue constants early
    float cch[4], whv[4];
    #pragma unroll
    for (int n = 0; n < 4; ++n) {
        int h = wave * 64 + n * 16 + l15;
        cch[n] = cc[(size_t)b * 512 + h];
        whv[n] = w2h[h];
    }

    // zero LDS pad rows (98..111) in both buffers; zero score accumulator
    for (int i = tid; i < 14 * 64; i += 512) { A[0][98 * 64 + i] = 0; A[1][98 * 64 + i] = 0; }
    if (tid < 112) slds[tid] = 0.0f;

    f32x4 acc[7][4];
    #pragma unroll
    for (int m = 0; m < 7; ++m)
        #pragma unroll
        for (int n = 0; n < 4; ++n) acc[m][n] = (f32x4){0.f, 0.f, 0.f, 0.f};

    float4 xvA[2][2], xvB[2][2];
    bf16x8 br[8];

    // prologue: issue loads for steps 0 and 1, stage step 0
    sc_xload(c, 0, xvA);
    sc_xload(c, 1, xvB);
    sc_stagewrite(c, 0, xvA);
    __syncthreads();

    #pragma unroll 1
    for (int t2 = 0; t2 < NSTEP; t2 += 2) {
        // even step t2: compute buf0, prefetch X(t2+2) into xvA, stage X(t2+1)->buf1
        if (t2 + 2 < NSTEP) sc_xload(c, t2 + 2, xvA);
        sc_bload(c, t2, br);
        sc_compute(c, t2, br, acc);
        sc_stagewrite(c, t2 + 1, xvB);
        __syncthreads();
        // odd step t2+1: compute buf1, prefetch X(t2+3) into xvB, stage X(t2+2)->buf0
        if (t2 + 3 < NSTEP) sc_xload(c, t2 + 3, xvB);
        sc_bload(c, t2 + 1, br);
        sc_compute(c, t2 + 1, br, acc);
        if (t2 + 2 < NSTEP) sc_stagewrite(c, t2 + 2, xvA);
        __syncthreads();
    }

    // epilogue: score[s] = sum_h tanh(feat + cc[h]) * w2h[h]
    #pragma unroll
    for (int m = 0; m < 7; ++m) {
        #pragma unroll
        for (int i = 0; i < 4; ++i) {
            float p = 0.0f;
            #pragma unroll
            for (int n = 0; n < 4; ++n) {
                float x = acc[m][n][i] + cch[n];
                float th = 1.0f - 2.0f / (__expf(2.0f * x) + 1.0f);
                p += th * whv[n];
            }
            p += __shfl_xor(p, 1);
            p += __shfl_xor(p, 2);
            p += __shfl_xor(p, 4);
            p += __shfl_xor(p, 8);
            if (l15 == 0) atomicAdd(&slds[m * 16 + l4 * 4 + i], p);
        }
    }
    __syncthreads();
    if (tid < 98) scores[(size_t)b * 208 + s0 + tid] = slds[tid];
}

// ---------------- softmax over s (196) per b ----------------
__global__ void k_softmax(float* sc) {
    int b = blockIdx.x, t = threadIdx.x;
    __shared__ float red[8];
    float v = (t < 196) ? sc[(size_t)b * 208 + t] : -3.0e38f;
    float m = v;
    for (int o = 32; o > 0; o >>= 1) m = fmaxf(m, __shfl_xor(m, o));
    if ((t & 63) == 0) red[t >> 6] = m;
    __syncthreads();
    m = fmaxf(fmaxf(red[0], red[1]), fmaxf(red[2], red[3]));
    float e = (t < 196) ? __expf(v - m) : 0.0f;
    float s = e;
    for (int o = 32; o > 0; o >>= 1) s += __shfl_xor(s, o);
    if ((t & 63) == 0) red[4 + (t >> 6)] = s;
    __syncthreads();
    float tot = red[4] + red[5] + red[6] + red[7];
    if (t < 196) sc[(size_t)b * 208 + t] = e / tot;
}

// ---------------- img_attn[b][f] = sum_s a[b][s] * X[b][s][f] ----------------
__global__ void k_wsum(const float* __restrict__ X, const float* __restrict__ a,
                       float* __restrict__ out1) {
    __shared__ float als[196];
    int b = blockIdx.x >> 1;
    int fh = (blockIdx.x & 1) * 1024;
    int t = threadIdx.x;
    if (t < 196) als[t] = a[(size_t)b * 208 + t];
    __syncthreads();
    int f = fh + t * 4;
    const float* Xb = X + (size_t)b * 196 * 2048 + f;
    float4 acc = {0.f, 0.f, 0.f, 0.f};
    #pragma unroll 4
    for (int s = 0; s < 196; ++s) {
        float4 x = *reinterpret_cast<const float4*>(Xb + (size_t)s * 2048);
        float w = als[s];
        acc.x += w * x.x; acc.y += w * x.y; acc.z += w * x.z; acc.w += w * x.w;
    }
    *reinterpret_cast<float4*>(out1 + (size_t)b * 2048 + f) = acc;
}

extern "C" void kernel_launch(void* const* d_in, const int* in_sizes, int n_in,
                              void* d_out, int out_size, void* d_ws, size_t ws_size,
                              hipStream_t stream) {
    const float* qf  = (const float*)d_in[0];
    const float* X   = (const float*)d_in[1];
    const float* w2x = (const float*)d_in[6];
    const float* b2x = (const float*)d_in[7];
    const float* w2g = (const float*)d_in[8];
    const float* b2g = (const float*)d_in[9];
    const float* w2h = (const float*)d_in[10];

    float* out0 = (float*)d_out;                 // ques_attn = ques_feat (512x1024)
    float* out1 = out0 + 512 * 1024;             // img_attn (512x2048)

    // ws layout: [0,2MB) WTf bf16 packed; [2MB,3MB) cc f32; [3MB,..) scores f32 (512x208)
    unsigned short* WTf = (unsigned short*)d_ws;
    float* cc = (float*)((char*)d_ws + (size_t)(2u << 20));
    float* sc = (float*)((char*)d_ws + (size_t)(3u << 20));

    k_copy<<<512, 256, 0, stream>>>(qf, out0);
    k_pack_w<<<1024, 128, 0, stream>>>(w2x, WTf);
    k_cconst<<<256, 256, 0, stream>>>(qf, w2g, b2g, b2x, cc);
    k_scores<<<1024, 512, 0, stream>>>(X, WTf, cc, w2h, sc);
    k_softmax<<<512, 256, 0, stream>>>(sc);
    k_wsum<<<1024, 256, 0, stream>>>(X, sc, out1);
}